// Round 6
// baseline (2854.947 us; speedup 1.0000x reference)
//
#include <hip/hip_runtime.h>

// DSTP-RNN: B=1024, T_ENC=48, 30 decoder steps, H=128, F=17.
// Round 6: BBLK=1, GRID=1024 -> 4 blocks/CU (32 waves, full occupancy).
// fp16 weights + v_dot2_f32_f16; fin/ud/pre2 all LDS-resident fp16;
// split serial chains (score/wd/din) for the 1-batch regime.

#define T_ENC 48
#define H 128
#define FDIM 17
#define NTH 512
#define GRID 1024

// ---- ws HALF offsets ----
#define H_WT1   0          // 19*512*8  = 77824  (e1 gates, [k8][j][8h], K pad 152)
#define H_WT2   77824      // 33*512*8  = 135168 (e2, K pad 264)
#define H_WTD   212992     // 32*512*8  = 131072 (dec, K=256)
#define H_WE1T  344064     // 128*48*2  = 12288  (We1^T pairs, uint idx k2*48+s)
#define H_WE2T  356352     // 12288
#define H_WDT   368640     // 128*128*2 = 32768  (Wd^T pairs, uint idx k2*128+sp)
#define H_UDT   401408     // 64*128*2  = 16384  (Ud^T pairs, uint idx k2*128+h)
// halves end at 417792 -> 835584 B = 208896 floats
// ---- ws FLOAT offsets ----
#define F_B1    208896
#define F_B2    209408
#define F_BD    209920
#define F_MID   210432     // 1024*48*129 fp32 mid [b][t][129]

typedef _Float16 h2_t __attribute__((ext_vector_type(2)));
union H2U { h2_t h; uint u; float f; };

__device__ __forceinline__ h2_t uh(uint v){ H2U x; x.u = v; return x.h; }
__device__ __forceinline__ h2_t fh(float v){ H2U x; x.f = v; return x.h; }
__device__ __forceinline__ uint pack2(float a, float b){
    H2U x; x.h[0] = (_Float16)a; x.h[1] = (_Float16)b; return x.u;
}
__device__ __forceinline__ float dot2f(h2_t a, h2_t b, float c){
#if __has_builtin(__builtin_amdgcn_fdot2)
    return __builtin_amdgcn_fdot2(a, b, c, false);
#else
    return c + (float)a[0]*(float)b[0] + (float)a[1]*(float)b[1];
#endif
}

__device__ __forceinline__ float fast_sigm(float x){
    return __fdividef(1.0f, 1.0f + __expf(-x));
}
__device__ __forceinline__ float fast_tanh(float x){
    float xc = fminf(fmaxf(x, -9.0f), 9.0f);
    float e = __expf(2.0f * xc);
    return __fdividef(e - 1.0f, e + 1.0f);
}

// ---------------- prologue: transpose/fuse weights into ws (fp16) ----------------
__global__ void prep_kernel(const float* __restrict__ We1W, const float* __restrict__ We2W,
                            const float* __restrict__ WdW,  const float* __restrict__ UdW,
                            const float* __restrict__ e1Wih, const float* __restrict__ e1Whh,
                            const float* __restrict__ e1bih, const float* __restrict__ e1bhh,
                            const float* __restrict__ e2Wih, const float* __restrict__ e2Whh,
                            const float* __restrict__ e2bih, const float* __restrict__ e2bhh,
                            const float* __restrict__ dWih,  const float* __restrict__ dWhh,
                            const float* __restrict__ dbih,  const float* __restrict__ dbhh,
                            float* __restrict__ ws)
{
    int idx = blockIdx.x * blockDim.x + threadIdx.x;
    _Float16* wsh = (_Float16*)ws;
    if (idx < 77824) {                       // WT1 [k8][j][8]: k<17 Wih, k<145 Whh, else 0
        int k8 = idx >> 12, r = idx & 4095, j = r >> 3, kq = r & 7, k = k8*8 + kq;
        float v = 0.f;
        if (k < 17) v = e1Wih[j*17 + k]; else if (k < 145) v = e1Whh[j*128 + (k-17)];
        wsh[H_WT1 + idx] = (_Float16)v; return;
    }
    idx -= 77824;
    if (idx < 135168) {                      // WT2: k<129 Wih, k<257 Whh, else 0 (pad 264)
        int k8 = idx >> 12, r = idx & 4095, j = r >> 3, kq = r & 7, k = k8*8 + kq;
        float v = 0.f;
        if (k < 129) v = e2Wih[j*129 + k]; else if (k < 257) v = e2Whh[j*128 + (k-129)];
        wsh[H_WT2 + idx] = (_Float16)v; return;
    }
    idx -= 135168;
    if (idx < 131072) {                      // WTD: k<128 Wih else Whh (K=256)
        int k8 = idx >> 12, r = idx & 4095, j = r >> 3, kq = r & 7, k = k8*8 + kq;
        float v = (k < 128) ? dWih[j*128 + k] : dWhh[j*128 + (k-128)];
        wsh[H_WTD + idx] = (_Float16)v; return;
    }
    idx -= 131072;
    if (idx < 12288) {                       // We1^T pairs
        int pr = idx >> 1, p = idx & 1, k2 = pr / 48, s = pr % 48;
        wsh[H_WE1T + idx] = (_Float16)We1W[s*256 + 2*k2 + p]; return;
    }
    idx -= 12288;
    if (idx < 12288) {
        int pr = idx >> 1, p = idx & 1, k2 = pr / 48, s = pr % 48;
        wsh[H_WE2T + idx] = (_Float16)We2W[s*256 + 2*k2 + p]; return;
    }
    idx -= 12288;
    if (idx < 32768) {                       // Wd^T pairs
        int pr = idx >> 1, p = idx & 1, k2 = pr >> 7, sp = pr & 127;
        wsh[H_WDT + idx] = (_Float16)WdW[sp*256 + 2*k2 + p]; return;
    }
    idx -= 32768;
    if (idx < 16384) {                       // Ud^T pairs
        int pr = idx >> 1, p = idx & 1, k2 = pr >> 7, hh = pr & 127;
        wsh[H_UDT + idx] = (_Float16)UdW[hh*128 + 2*k2 + p]; return;
    }
    idx -= 16384;
    if (idx < 512) { ws[F_B1 + idx] = e1bih[idx] + e1bhh[idx]; return; }
    idx -= 512;
    if (idx < 512) { ws[F_B2 + idx] = e2bih[idx] + e2bhh[idx]; return; }
    idx -= 512;
    if (idx < 512) { ws[F_BD + idx] = dbih[idx] + dbhh[idx]; return; }
}

// gate matmul, 1 batch, 2 independent acc chains: g[j]=bias[j]+sum_k u[k]*W[k][j]
template<int K8>
__device__ __forceinline__ void lstm_gates1h(const float4* __restrict__ W8,
                                             const float* __restrict__ bias,
                                             const uint* u2, float* g, int tid)
{
    float a0 = bias[tid], a1 = 0.f;
    #pragma unroll
    for (int k8 = 0; k8 + 1 < K8; k8 += 2) {
        float4 w0 = W8[k8*512 + tid];
        float4 w1 = W8[(k8+1)*512 + tid];
        float4 u0 = *(const float4*)(u2 + 4*k8);
        float4 u1 = *(const float4*)(u2 + 4*k8 + 4);
        a0 = dot2f(fh(w0.x), fh(u0.x), a0); a0 = dot2f(fh(w0.y), fh(u0.y), a0);
        a0 = dot2f(fh(w0.z), fh(u0.z), a0); a0 = dot2f(fh(w0.w), fh(u0.w), a0);
        a1 = dot2f(fh(w1.x), fh(u1.x), a1); a1 = dot2f(fh(w1.y), fh(u1.y), a1);
        a1 = dot2f(fh(w1.z), fh(u1.z), a1); a1 = dot2f(fh(w1.w), fh(u1.w), a1);
    }
    if (K8 & 1) {
        float4 w0 = W8[(K8-1)*512 + tid];
        float4 u0 = *(const float4*)(u2 + 4*(K8-1));
        a0 = dot2f(fh(w0.x), fh(u0.x), a0); a0 = dot2f(fh(w0.y), fh(u0.y), a0);
        a0 = dot2f(fh(w0.z), fh(u0.z), a0); a0 = dot2f(fh(w0.w), fh(u0.w), a0);
    }
    g[tid] = a0 + a1;
}

// single-row softmax, one wave
__device__ __forceinline__ void softmax1(float* sc, float* at, int n, int tid)
{
    if (tid < 64) {
        float m = -1e30f;
        for (int f = tid; f < n; f += 64) m = fmaxf(m, sc[f]);
        for (int o = 32; o; o >>= 1) m = fmaxf(m, __shfl_xor(m, o));
        float ssum = 0.f;
        for (int f = tid; f < n; f += 64) { float p = __expf(sc[f] - m); at[f] = p; ssum += p; }
        for (int o = 32; o; o >>= 1) ssum += __shfl_xor(ssum, o);
        float inv = __fdividef(1.f, ssum);
        for (int f = tid; f < n; f += 64) at[f] *= inv;
    }
}

// we[s] = [h;c] @ W^T, 384 threads = s(48) x kq(8), 16 pairs each, shfl-reduce
__device__ __forceinline__ void we_phase1(const uint* __restrict__ W2,
                                          const uint* h2, const uint* c2,
                                          float* sh_we, int tid)
{
    if (tid < 384) {
        int s = tid >> 3, kq = tid & 7;
        const uint* st2 = ((kq < 4) ? h2 : c2) + (kq & 3)*16;
        const uint* w2  = W2 + (kq*16)*48 + s;
        float acc = 0.f;
        #pragma unroll
        for (int i = 0; i < 16; ++i)
            acc = dot2f(uh(st2[i]), uh(w2[i*48]), acc);
        acc += __shfl_xor(acc, 1);
        acc += __shfl_xor(acc, 2);
        acc += __shfl_xor(acc, 4);
        if (kq == 0) sh_we[s] = acc;
    }
}

__global__ __launch_bounds__(NTH, 8)
void dstp_main(const float* __restrict__ ipq,  const float* __restrict__ labp,
               const float* __restrict__ Ue1W, const float* __restrict__ Ue1b,
               const float* __restrict__ Ve1,  const float* __restrict__ Ve1b,
               const float* __restrict__ Ue2W, const float* __restrict__ Ue2b,
               const float* __restrict__ Ve2,  const float* __restrict__ Ve2b,
               const float* __restrict__ Udb,
               const float* __restrict__ Vd,   const float* __restrict__ Vdb,
               const float* __restrict__ regW, const float* __restrict__ regb,
               float* __restrict__ ws, float* __restrict__ out)
{
    extern __shared__ float sm[];
    float* sh_h   = sm;            // 128
    float* sh_c   = sm + 128;      // 128
    float* sh_we  = sm + 256;      // 64 (48 used)
    float* sh_sc  = sm + 320;      // 132
    float* sh_sc2 = sm + 452;      // 132 (score partials)
    float* sh_at  = sm + 584;      // 132
    float* sh_g   = sm + 716;      // 512 (gates / wd partials)
    float* sh_x   = sm + 1228;     // 816 x[48][17]
    float* sh_p1  = sm + 2044;     // 816 pre1[s][f]
    uint*  sh_h2u = (uint*)(sm + 2860);   // 64 h fp16 pairs
    uint*  sh_c2u = (uint*)(sm + 2924);   // 64
    uint*  sh_u2  = (uint*)(sm + 2988);   // 136 (132 used; 16B aligned)
    _Float16* sh_p2h = (_Float16*)(sm + 3124); // 6240 halves [48][130]: pre2, then ud
    _Float16* sh_fnh = (_Float16*)(sm + 6244); // 6144 halves [48][128]: fin
    uint*     sh_fn2 = (uint*)(sm + 6244);     // pair view [48][64]
    // total 9316 floats = 37,264 B -> 4 blocks/CU (149 KB of 160)

    const int tid = threadIdx.x;
    const int b0  = blockIdx.x;                // 1 batch per block
    const _Float16* wsh = (const _Float16*)ws;

    // ---- phase 0 ----
    for (int idx = tid; idx < T_ENC*FDIM; idx += NTH) {
        int t = idx / FDIM, f = idx % FDIM;
        sh_x[idx] = ipq[((size_t)b0*T_ENC + t)*18 + 1 + f];
    }
    if (tid < 128) { sh_h[tid] = 0.f; sh_c[tid] = 0.f; }
    if (tid < 64)  { sh_h2u[tid] = 0u; sh_c2u[tid] = 0u; }
    if (tid < T_ENC)
        ws[F_MID + ((size_t)b0*T_ENC + tid)*129 + 128] = labp[(size_t)b0*T_ENC + tid];
    __syncthreads();
    for (int idx = tid; idx < T_ENC*FDIM; idx += NTH) {   // pre1[s][f]
        int s = idx / FDIM, f = idx % FDIM;
        float acc = Ue1b[s];
        #pragma unroll 4
        for (int t = 0; t < T_ENC; ++t) acc = fmaf(sh_x[t*FDIM + f], Ue1W[s*T_ENC + t], acc);
        sh_p1[idx] = acc;
    }
    __syncthreads();

    // ============================ stage 1 ============================
    const float ve1b = Ve1b[0];
    for (int t = 0; t < T_ENC; ++t) {
        we_phase1((const uint*)(wsh + H_WE1T), sh_h2u, sh_c2u, sh_we, tid);
        __syncthreads();
        if (tid < 68) {                           // score[f], 4 lanes per f
            int f = tid >> 2, q = tid & 3;
            float acc = 0.f;
            for (int s = q; s < 48; s += 4)
                acc += fast_tanh(sh_we[s] + sh_p1[s*FDIM + f]) * Ve1[s];
            acc += __shfl_xor(acc, 1);
            acc += __shfl_xor(acc, 2);
            if (q == 0) sh_sc[f] = acc + ve1b;
        }
        __syncthreads();
        softmax1(sh_sc, sh_at, FDIM, tid);
        __syncthreads();
        if (tid < 152) {                          // u fp16 = [x_t*attn(17), h(128), pad]
            int kk = tid;
            float v;
            if (kk < FDIM)        v = sh_x[t*FDIM + kk] * sh_at[kk];
            else if (kk < FDIM+H) v = sh_h[kk - FDIM];
            else                  v = 0.f;
            float vnb = __shfl_xor(v, 1);
            if (!(kk & 1)) sh_u2[kk >> 1] = pack2(v, vnb);
        }
        __syncthreads();
        lstm_gates1h<19>((const float4*)(wsh + H_WT1), ws + F_B1, sh_u2, sh_g, tid);
        __syncthreads();
        if (tid < 128) {                          // LSTM update; mid row -> ws
            int jj = tid;
            float gi = sh_g[jj],       gf = sh_g[128 + jj];
            float gg = sh_g[256 + jj], go = sh_g[384 + jj];
            float c2v = fast_sigm(gf)*sh_c[jj] + fast_sigm(gi)*fast_tanh(gg);
            float hn  = fast_sigm(go)*fast_tanh(c2v);
            sh_c[jj] = c2v; sh_h[jj] = hn;
            ws[F_MID + ((size_t)b0*T_ENC + t)*129 + jj] = hn;
            float hnb = __shfl_xor(hn, 1), cnb = __shfl_xor(c2v, 1);
            if (!(jj & 1)) {
                sh_h2u[jj >> 1] = pack2(hn, hnb);
                sh_c2u[jj >> 1] = pack2(c2v, cnb);
            }
        }
        __syncthreads();
    }

    // ---- transition: pre2 fp16 -> LDS [s][130]; reset state ----
    for (int idx = tid; idx < 48*129; idx += NTH) {
        int s = idx / 129, f = idx % 129;
        const float* midb = ws + F_MID + (size_t)b0*T_ENC*129 + f;
        float acc = Ue2b[s];
        #pragma unroll 4
        for (int t2 = 0; t2 < T_ENC; ++t2) acc = fmaf(midb[t2*129], Ue2W[s*48 + t2], acc);
        sh_p2h[s*130 + f] = (_Float16)acc;
    }
    if (tid < 128) { sh_h[tid] = 0.f; sh_c[tid] = 0.f; }
    if (tid < 64)  { sh_h2u[tid] = 0u; sh_c2u[tid] = 0u; }
    __syncthreads();

    // ============================ stage 2 ============================
    const float ve2b = Ve2b[0];
    for (int t = 0; t < T_ENC; ++t) {
        we_phase1((const uint*)(wsh + H_WE2T), sh_h2u, sh_c2u, sh_we, tid);
        __syncthreads();
        if (tid < 258) {                          // score partials: 129 f x 2 s-halves
            int f = (tid < 129) ? tid : tid - 129;
            int s0 = (tid < 129) ? 0 : 24;
            const _Float16* p2 = sh_p2h + f;
            float acc = 0.f;
            #pragma unroll 4
            for (int s = s0; s < s0 + 24; ++s)
                acc += fast_tanh(sh_we[s] + (float)p2[s*130]) * Ve2[s];
            ((tid < 129) ? sh_sc : sh_sc2)[f] = acc;
        }
        __syncthreads();
        if (tid < 129) sh_sc[tid] = sh_sc[tid] + sh_sc2[tid] + ve2b;
        __syncthreads();
        softmax1(sh_sc, sh_at, 129, tid);
        __syncthreads();
        if (tid < 264) {                          // u fp16 = [m_t*attn(129), h(128), pad]
            int kk = tid;
            const float* midrow = ws + F_MID + ((size_t)b0*T_ENC + t)*129;
            float v;
            if (kk < 129)      v = midrow[kk] * sh_at[kk];
            else if (kk < 257) v = sh_h[kk - 129];
            else               v = 0.f;
            float vnb = __shfl_xor(v, 1);
            if (!(kk & 1)) sh_u2[kk >> 1] = pack2(v, vnb);
        }
        __syncthreads();
        lstm_gates1h<33>((const float4*)(wsh + H_WT2), ws + F_B2, sh_u2, sh_g, tid);
        __syncthreads();
        if (tid < 128) {                          // update; fin fp16 -> LDS only
            int jj = tid;
            float gi = sh_g[jj],       gf = sh_g[128 + jj];
            float gg = sh_g[256 + jj], go = sh_g[384 + jj];
            float c2v = fast_sigm(gf)*sh_c[jj] + fast_sigm(gi)*fast_tanh(gg);
            float hn  = fast_sigm(go)*fast_tanh(c2v);
            sh_c[jj] = c2v; sh_h[jj] = hn;
            sh_fnh[t*128 + jj] = (_Float16)hn;
            float hnb = __shfl_xor(hn, 1), cnb = __shfl_xor(c2v, 1);
            if (!(jj & 1)) {
                sh_h2u[jj >> 1] = pack2(hn, hnb);
                sh_c2u[jj >> 1] = pack2(c2v, cnb);
            }
        }
        __syncthreads();
    }

    // ---- transition: ud = fin @ Ud^T + Udb, LDS->LDS (overwrites dead pre2) ----
    {
        int hh = tid & 127, tg = tid >> 7;        // 4 t-groups, 12 t each
        float acc[12];
        float ub = Udb[hh];
        #pragma unroll
        for (int i = 0; i < 12; ++i) acc[i] = ub;
        const uint* UT2 = (const uint*)(wsh + H_UDT);
        for (int k2 = 0; k2 < 64; ++k2) {
            h2_t w2 = uh(UT2[k2*128 + hh]);
            #pragma unroll
            for (int i = 0; i < 12; ++i)
                acc[i] = dot2f(uh(sh_fn2[(tg + 4*i)*64 + k2]), w2, acc[i]);
        }
        #pragma unroll
        for (int i = 0; i < 12; ++i)
            sh_p2h[(tg + 4*i)*130 + hh] = (_Float16)acc[i];   // ud[t][h]
    }
    if (tid < 128) { sh_h[tid] = 0.f; sh_c[tid] = 0.f; }
    if (tid < 64)  { sh_h2u[tid] = 0u; sh_c2u[tid] = 0u; }
    __syncthreads();

    // ============================ decoder ============================
    const float vdb = Vdb[0], rb = regb[0];
    for (int st = 0; st < 30; ++st) {
        {   // wd partials, 4-way split-K: sh_g[kq*128+sp]
            int kq = tid >> 7, sp = tid & 127;
            const uint* st2 = ((kq < 2) ? sh_h2u : sh_c2u) + (kq & 1)*32;
            const uint* W2  = (const uint*)(wsh + H_WDT) + (kq*32)*128 + sp;
            float acc = 0.f;
            #pragma unroll 8
            for (int i = 0; i < 32; ++i)
                acc = dot2f(uh(st2[i]), uh(W2[i*128]), acc);
            sh_g[kq*128 + sp] = acc;
        }
        __syncthreads();
        if (tid < 192) {                           // score[t], 4 lanes x 32 h each
            int tt = tid >> 2, q = tid & 3, h0 = q*32;
            const _Float16* udrow = sh_p2h + tt*130;
            float acc = 0.f;
            #pragma unroll 4
            for (int kk = 0; kk < 32; ++kk) {
                int hh = h0 + kk;
                float wd = sh_g[hh] + sh_g[128 + hh] + sh_g[256 + hh] + sh_g[384 + hh];
                acc += fast_tanh(wd + (float)udrow[hh]) * Vd[hh];
            }
            acc += __shfl_xor(acc, 1);
            acc += __shfl_xor(acc, 2);
            if (q == 0) sh_sc[tt] = acc + vdb;
        }
        __syncthreads();
        softmax1(sh_sc, sh_at, 48, tid);
        __syncthreads();
        if (tid < 256) {                           // din[h] = attn @ fin (fp16 LDS), pack
            int q = tid & 1, hh = tid >> 1;
            float acc = 0.f;
            for (int tt = q; tt < 48; tt += 2)
                acc = fmaf(sh_at[tt], (float)sh_fnh[tt*128 + hh], acc);
            acc += __shfl_xor(acc, 1);             // full din[hh] on both lanes
            float anb = __shfl_xor(acc, 2);        // din[hh^1] partner
            if (!(tid & 3)) sh_u2[tid >> 2] = pack2(acc, anb);
        }
        if (tid < 64) sh_u2[64 + tid] = sh_h2u[tid];   // u[128..255] = h pairs
        __syncthreads();
        lstm_gates1h<32>((const float4*)(wsh + H_WTD), ws + F_BD, sh_u2, sh_g, tid);
        __syncthreads();
        if (tid < 128) {
            int jj = tid;
            float gi = sh_g[jj],       gf = sh_g[128 + jj];
            float gg = sh_g[256 + jj], go = sh_g[384 + jj];
            float c2v = fast_sigm(gf)*sh_c[jj] + fast_sigm(gi)*fast_tanh(gg);
            float hn  = fast_sigm(go)*fast_tanh(c2v);
            sh_c[jj] = c2v; sh_h[jj] = hn;
            float hnb = __shfl_xor(hn, 1), cnb = __shfl_xor(c2v, 1);
            if (!(jj & 1)) {
                sh_h2u[jj >> 1] = pack2(hn, hnb);
                sh_c2u[jj >> 1] = pack2(c2v, cnb);
            }
        }
        __syncthreads();
        if (st >= 6 && tid < 64) {                 // out[b][st-6] (reads only sh_h)
            float v = sh_h[tid]*regW[tid] + sh_h[64 + tid]*regW[64 + tid];
            for (int o = 32; o; o >>= 1) v += __shfl_xor(v, o);
            if (tid == 0) out[(size_t)b0*24 + (st - 6)] = v + rb;
        }
        // next wd phase only READS h2u/c2u (written before last barrier) -> safe
    }
}

extern "C" void kernel_launch(void* const* d_in, const int* in_sizes, int n_in,
                              void* d_out, int out_size, void* d_ws, size_t ws_size,
                              hipStream_t stream)
{
    const float* ipq   = (const float*)d_in[0];
    const float* labp  = (const float*)d_in[1];
    const float* Ue1W  = (const float*)d_in[2];
    const float* Ue1b  = (const float*)d_in[3];
    const float* We1W  = (const float*)d_in[4];
    const float* Ve1   = (const float*)d_in[5];
    const float* Ve1b  = (const float*)d_in[6];
    const float* Ue2W  = (const float*)d_in[7];
    const float* Ue2b  = (const float*)d_in[8];
    const float* We2W  = (const float*)d_in[9];
    const float* Ve2   = (const float*)d_in[10];
    const float* Ve2b  = (const float*)d_in[11];
    const float* UdW   = (const float*)d_in[12];
    const float* Udb   = (const float*)d_in[13];
    const float* WdW   = (const float*)d_in[14];
    const float* Vd    = (const float*)d_in[15];
    const float* Vdb   = (const float*)d_in[16];
    const float* e1Wih = (const float*)d_in[17];
    const float* e1Whh = (const float*)d_in[18];
    const float* e1bih = (const float*)d_in[19];
    const float* e1bhh = (const float*)d_in[20];
    const float* e2Wih = (const float*)d_in[21];
    const float* e2Whh = (const float*)d_in[22];
    const float* e2bih = (const float*)d_in[23];
    const float* e2bhh = (const float*)d_in[24];
    const float* dWih  = (const float*)d_in[25];
    const float* dWhh  = (const float*)d_in[26];
    const float* dbih  = (const float*)d_in[27];
    const float* dbhh  = (const float*)d_in[28];
    const float* regW  = (const float*)d_in[29];
    const float* regb  = (const float*)d_in[30];
    float* ws  = (float*)d_ws;
    float* out = (float*)d_out;

    // weights: 417792 halves; biases: 1536 floats
    prep_kernel<<<(417792 + 1536 + 255)/256, 256, 0, stream>>>(
        We1W, We2W, WdW, UdW,
        e1Wih, e1Whh, e1bih, e1bhh,
        e2Wih, e2Whh, e2bih, e2bhh,
        dWih, dWhh, dbih, dbhh, ws);

    const size_t smem = 9316u * sizeof(float);    // 37,264 B -> 4 blocks/CU
    hipFuncSetAttribute((const void*)dstp_main,
                        hipFuncAttributeMaxDynamicSharedMemorySize, (int)smem);
    dstp_main<<<GRID, NTH, smem, stream>>>(
        ipq, labp, Ue1W, Ue1b, Ve1, Ve1b,
        Ue2W, Ue2b, Ve2, Ve2b,
        Udb, Vd, Vdb, regW, regb, ws, out);
}